// Round 9
// baseline (390.603 us; speedup 1.0000x reference)
//
#include <hip/hip_runtime.h>
#include <hip/hip_bf16.h>
#include <cstdint>
#include <cstddef>

#define NUM_NODES 500000
#define DIM 128
#define BATCH 131072

typedef __attribute__((ext_vector_type(8))) short short8;
typedef __attribute__((ext_vector_type(4))) float f32x4;

static __device__ __forceinline__ short f2bf(float f) {
    unsigned u = __builtin_bit_cast(unsigned, f);
    u += 0x7fffu + ((u >> 16) & 1u);   // round-to-nearest-even
    return (short)(u >> 16);
}

static __device__ __forceinline__ short8 cvt8(const float* __restrict__ p) {
    f32x4 a = *(const f32x4*)p;
    f32x4 b = *(const f32x4*)(p + 4);
    short8 s;
    s[0] = f2bf(a.x); s[1] = f2bf(a.y); s[2] = f2bf(a.z); s[3] = f2bf(a.w);
    s[4] = f2bf(b.x); s[5] = f2bf(b.y); s[6] = f2bf(b.z); s[7] = f2bf(b.w);
    return s;
}

// ---------------------------------------------------------------- init ----
__global__ void k_init(unsigned char* __restrict__ mask,
                       const float* __restrict__ Wih,
                       const float* __restrict__ Whh,
                       short* __restrict__ WbIH,
                       short* __restrict__ WbHH,
                       int do_mask) {
    int i = blockIdx.x * blockDim.x + threadIdx.x;
    if (do_mask && i < NUM_NODES) mask[i] = 0;
    if (i < 3 * DIM * DIM) {
        WbIH[i] = f2bf(Wih[i]);
        WbHH[i] = f2bf(Whh[i]);
    }
}

__global__ void k_scatter(unsigned char* __restrict__ mask, const int* __restrict__ idx) {
    int i = blockIdx.x * blockDim.x + threadIdx.x;
    if (i < BATCH) mask[idx[i]] = 1;
}

// ---------------------------------------------------------------- copy ----
// FROZEN from R5 (A/B isolation): 256 thr, no LDS, 16 thr/row, 32B/plane.
__global__ void __launch_bounds__(256)
k_copy(const float* __restrict__ hidden,
       const float* __restrict__ variance,
       const unsigned char* __restrict__ mask,   // null -> copy all
       float* __restrict__ out0,
       float* __restrict__ out1) {
    int gid = blockIdx.x * 256 + threadIdx.x;
    int row = gid >> 4;
    int c8  = gid & 15;
    if (mask && mask[row]) return;               // gru writes this row
    size_t off = (size_t)row * DIM + c8 * 8;
    f32x4 a0 = *(const f32x4*)(hidden + off);
    f32x4 a1 = *(const f32x4*)(hidden + off + 4);
    f32x4 b0 = *(const f32x4*)(variance + off);
    f32x4 b1 = *(const f32x4*)(variance + off + 4);
    *(f32x4*)(out0 + off)     = a0;
    *(f32x4*)(out0 + off + 4) = a1;
    *(f32x4*)(out1 + off)     = b0;
    *(f32x4*)(out1 + off + 4) = b1;
}

// ----------------------------------------------------------------- gru ----
// v9: ZERO LDS, ZERO BARRIERS. 512 thr = 8 waves, 32 rows/block, 4096 blocks.
// Lane (c,gq) of every wave loads its MFMA A-fragments (x and gathered h rows
// rb+c / rb+16+c, 32B k-slices) DIRECTLY from global, converts f32->bf16 in
// registers. Wave access = 16 dense 128B segments per ks step (coalesced for
// any idx). No collective stalls; compiler software-pipelines the ks loop.
// Epilogue: exact-f32 h re-read (L1-hot), fused variance, direct stores.
__global__ void __launch_bounds__(512)
k_gru(const float* __restrict__ hidden,
      const float* __restrict__ variance,
      const int*   __restrict__ idx,
      const float* __restrict__ xg,       // new_repr
      const short* __restrict__ WbIH,     // [384][128] bf16 bits
      const short* __restrict__ WbHH,
      const float* __restrict__ b_ih,
      const float* __restrict__ b_hh,
      float* __restrict__ out0,
      float* __restrict__ out1) {
    const int t  = threadIdx.x;
    const int w  = t >> 6;       // wave id 0..7 -> output dims 16w..16w+15
    const int l  = t & 63;
    const int c  = l & 15;
    const int gq = l >> 4;
    const int rb = blockIdx.x * 32;

    const int r0 = rb + c, r1 = rb + 16 + c;
    const int n0 = idx[r0], n1 = idx[r1];
    const float* xp0 = xg + (size_t)r0 * DIM;
    const float* xp1 = xg + (size_t)r1 * DIM;
    const float* hp0 = hidden + (size_t)n0 * DIM;
    const float* hp1 = hidden + (size_t)n1 * DIM;

    f32x4 acc[2][3][2] = {};     // [m-tile][gate third][0=x@Wih 1=h@Whh]

    #pragma unroll
    for (int ks = 0; ks < 4; ++ks) {
        const int k0 = ks * 32 + gq * 8;
        const short8 aX0 = cvt8(xp0 + k0);
        const short8 aX1 = cvt8(xp1 + k0);
        const short8 aH0 = cvt8(hp0 + k0);
        const short8 aH1 = cvt8(hp1 + k0);
        #pragma unroll
        for (int th = 0; th < 3; ++th) {
            const int o = w * 16 + th * 128 + c;        // gate output row of W
            const short8 bi = *(const short8*)(WbIH + (size_t)o * DIM + k0);
            const short8 bh = *(const short8*)(WbHH + (size_t)o * DIM + k0);
            acc[0][th][0] = __builtin_amdgcn_mfma_f32_16x16x32_bf16(aX0, bi, acc[0][th][0], 0, 0, 0);
            acc[1][th][0] = __builtin_amdgcn_mfma_f32_16x16x32_bf16(aX1, bi, acc[1][th][0], 0, 0, 0);
            acc[0][th][1] = __builtin_amdgcn_mfma_f32_16x16x32_bf16(aH0, bh, acc[0][th][1], 0, 0, 0);
            acc[1][th][1] = __builtin_amdgcn_mfma_f32_16x16x32_bf16(aH1, bh, acc[1][th][1], 0, 0, 0);
        }
    }

    // ---- gate math; lane holds (m = mt*16 + gq*4 + r, d = 16w + c) ----
    const int d = w * 16 + c;
    const float bs_r = b_ih[d]       + b_hh[d];
    const float bs_z = b_ih[d + 128] + b_hh[d + 128];
    const float bi_n = b_ih[d + 256];
    const float bh_n = b_hh[d + 256];

    #pragma unroll
    for (int mt = 0; mt < 2; ++mt) {
        #pragma unroll
        for (int r = 0; r < 4; ++r) {
            const int m = mt * 16 + gq * 4 + r;
            float s_r  = acc[mt][0][0][r] + acc[mt][0][1][r] + bs_r;
            float s_z  = acc[mt][1][0][r] + acc[mt][1][1][r] + bs_z;
            float gi_n = acc[mt][2][0][r] + bi_n;
            float gh_n = acc[mt][2][1][r] + bh_n;
            float rg = 1.f / (1.f + __expf(-s_r));
            float zg = 1.f / (1.f + __expf(-s_z));
            float aa = gi_n + rg * gh_n;
            float n  = 1.f - 2.f / (__expf(2.f * aa) + 1.f);   // tanh, inf-safe
            int node = idx[rb + m];                    // L1-hot
            size_t off = (size_t)node * DIM + d;
            float h  = hidden[off];                    // exact f32, L1-hot
            float hn = (1.f - zg) * n + zg * h;
            float dl = hn - h;
            out0[off] = hn;
            out1[off] = 0.9f * variance[off] + 0.1f * dl * dl;
        }
    }
}

// -------------------------------------------------------------- launch ----
extern "C" void kernel_launch(void* const* d_in, const int* in_sizes, int n_in,
                              void* d_out, int out_size, void* d_ws, size_t ws_size,
                              hipStream_t stream) {
    const float* hidden   = (const float*)d_in[0];
    const float* variance = (const float*)d_in[1];
    const int*   idx      = (const int*)d_in[2];
    const float* x        = (const float*)d_in[3];
    const float* Wih      = (const float*)d_in[4];
    const float* Whh      = (const float*)d_in[5];
    const float* bih      = (const float*)d_in[6];
    const float* bhh      = (const float*)d_in[7];
    float* out0 = (float*)d_out;
    float* out1 = out0 + (size_t)NUM_NODES * DIM;

    const size_t maskBytes = (size_t)NUM_NODES;               // 1 byte per node
    const size_t wBytes    = (size_t)3 * DIM * DIM * 2;       // per matrix (bf16)
    const bool   have_mask = ws_size >= maskBytes + 16 + 2 * wBytes;

    unsigned char* mask = have_mask ? (unsigned char*)d_ws : nullptr;
    short* WbIH = have_mask ? (short*)((char*)d_ws + ((maskBytes + 15) & ~size_t(15)))
                            : (short*)d_ws;
    short* WbHH = WbIH + 3 * DIM * DIM;

    k_init<<<(NUM_NODES + 255) / 256, 256, 0, stream>>>(
        mask ? mask : (unsigned char*)d_ws, Wih, Whh, WbIH, WbHH, have_mask ? 1 : 0);

    if (have_mask)
        k_scatter<<<BATCH / 256, 256, 0, stream>>>(mask, idx);

    // copy non-updated rows (copy-all if no mask), then gru writes its rows
    k_copy<<<(NUM_NODES * 16) / 256, 256, 0, stream>>>(
        hidden, variance, mask, out0, out1);

    k_gru<<<BATCH / 32, 512, 0, stream>>>(hidden, variance, idx, x,
                                          WbIH, WbHH, bih, bhh, out0, out1);
}

// Round 12
// 267.300 us; speedup vs baseline: 1.4613x; 1.4613x over previous
//
#include <hip/hip_runtime.h>
#include <hip/hip_bf16.h>
#include <cstdint>
#include <cstddef>

#define NUM_NODES 500000
#define DIM 128
#define BATCH 131072
#define NBLK (NUM_NODES / 32)     // 15625 exactly

typedef __attribute__((ext_vector_type(8))) short short8;
typedef __attribute__((ext_vector_type(4))) short short4_t;
typedef __attribute__((ext_vector_type(4))) float f32x4;

static __device__ __forceinline__ short f2bf(float f) {
    unsigned u = __builtin_bit_cast(unsigned, f);
    u += 0x7fffu + ((u >> 16) & 1u);   // round-to-nearest-even
    return (short)(u >> 16);
}
static __device__ __forceinline__ float bf2f(short s) {
    unsigned u = ((unsigned)(unsigned short)s) << 16;
    return __builtin_bit_cast(float, u);
}

// ---------------------------------------------------------------- init ----
__global__ void k_init(int* __restrict__ inv,            // may be null
                       unsigned char* __restrict__ mask, // may be null
                       const float* __restrict__ Wih,
                       const float* __restrict__ Whh,
                       short* __restrict__ WbIH,
                       short* __restrict__ WbHH) {
    int i = blockIdx.x * blockDim.x + threadIdx.x;
    if (i < NUM_NODES) {
        if (inv)  inv[i] = -1;
        if (mask) mask[i] = 0;
    }
    if (i < 3 * DIM * DIM) {
        WbIH[i] = f2bf(Wih[i]);
        WbHH[i] = f2bf(Whh[i]);
    }
}

__global__ void k_scatter(int* __restrict__ inv, unsigned char* __restrict__ mask,
                          const int* __restrict__ idx) {
    int i = blockIdx.x * blockDim.x + threadIdx.x;
    if (i < BATCH) {
        int n = idx[i];
        if (inv)  inv[n] = i;
        if (mask) mask[n] = 1;
    }
}

// --------------------------------------------------------------- stream ----
// ONE kernel over all rows, 512 thr = 8 waves, 32 sequential rows/block.
// No-update blocks: pure f32x4 copy. Update blocks: h/var read from LOCAL
// sequential rows (no gather), x fetched via inv (coalesced for arange idx),
// R5-proven MFMA core, h_new staged bf16 over dead Xb, coalesced epilogue.
__global__ void __launch_bounds__(512)
k_stream(const float* __restrict__ hidden,
         const float* __restrict__ variance,
         const int*   __restrict__ inv,
         const float* __restrict__ xg,
         const short* __restrict__ WbIH,     // [384][128] bf16 bits
         const short* __restrict__ WbHH,
         const float* __restrict__ b_ih,
         const float* __restrict__ b_hh,
         float* __restrict__ out0,
         float* __restrict__ out1) {
    __shared__ __align__(16) char smem[26112];
    short (*Xb)[136] = (short(*)[136])smem;             // bf16 x tile
    short (*Hb)[136] = (short(*)[136])(smem + 8704);    // bf16 h tile
    short (*Vb)[136] = (short(*)[136])(smem + 17408);   // bf16 variance tile
    short (*Hn)[136] = (short(*)[136])smem;             // bf16 h_new, overlays Xb
    __shared__ int rinfo[32];
    __shared__ int hasUpd;

    const int t  = threadIdx.x;
    const int rb = blockIdx.x * 32;

    if (t == 0) hasUpd = 0;
    if (t < 32) rinfo[t] = inv[rb + t];
    __syncthreads();
    if (t < 32 && rinfo[t] >= 0) hasUpd = 1;
    __syncthreads();

    if (!hasUpd) {
        // ---- pure copy: fully sequential streaming ----
        #pragma unroll
        for (int jj = 0; jj < 2; ++jj) {
            int j = t + jj * 512;
            size_t off = (size_t)rb * DIM + j * 4;      // rows sequential
            f32x4 h = *(const f32x4*)(hidden + off);
            f32x4 v = *(const f32x4*)(variance + off);
            *(f32x4*)(out0 + off) = h;
            *(f32x4*)(out1 + off) = v;
        }
        return;
    }

    // ---- stage: local h/var + inv-gathered x; copy-out non-updated rows ----
    #pragma unroll
    for (int jj = 0; jj < 2; ++jj) {
        int j = t + jj * 512;
        int row = j >> 5, c4 = j & 31;
        size_t off = (size_t)(rb + row) * DIM + c4 * 4;
        f32x4 hv = *(const f32x4*)(hidden + off);
        f32x4 vv = *(const f32x4*)(variance + off);
        int iv = rinfo[row];
        f32x4 xv = {0.f, 0.f, 0.f, 0.f};
        if (iv >= 0) {
            xv = *(const f32x4*)(xg + (size_t)iv * DIM + c4 * 4);
        } else {
            *(f32x4*)(out0 + off) = hv;                 // mixed block: copy now
            *(f32x4*)(out1 + off) = vv;
        }
        short4_t xs, hs, vs;
        xs.x = f2bf(xv.x); xs.y = f2bf(xv.y); xs.z = f2bf(xv.z); xs.w = f2bf(xv.w);
        hs.x = f2bf(hv.x); hs.y = f2bf(hv.y); hs.z = f2bf(hv.z); hs.w = f2bf(hv.w);
        vs.x = f2bf(vv.x); vs.y = f2bf(vv.y); vs.z = f2bf(vv.z); vs.w = f2bf(vv.w);
        *(short4_t*)&Xb[row][c4 * 4] = xs;
        *(short4_t*)&Hb[row][c4 * 4] = hs;
        *(short4_t*)&Vb[row][c4 * 4] = vs;
    }
    __syncthreads();

    const int w  = t >> 6;       // wave id 0..7 -> output dims 16w..16w+15
    const int l  = t & 63;
    const int c  = l & 15;
    const int gq = l >> 4;

    f32x4 acc[2][3][2] = {};     // [m-tile][gate third][0=x@Wih 1=h@Whh]

    #pragma unroll
    for (int ks = 0; ks < 4; ++ks) {
        const int k0 = ks * 32 + gq * 8;
        short8 a[2][2];
        a[0][0] = *(const short8*)&Xb[c][k0];
        a[1][0] = *(const short8*)&Xb[16 + c][k0];
        a[0][1] = *(const short8*)&Hb[c][k0];
        a[1][1] = *(const short8*)&Hb[16 + c][k0];
        #pragma unroll
        for (int th = 0; th < 3; ++th) {
            const int o = w * 16 + th * 128 + c;        // gate output row of W
            const short8 bi = *(const short8*)(WbIH + (size_t)o * DIM + k0);
            const short8 bh = *(const short8*)(WbHH + (size_t)o * DIM + k0);
            #pragma unroll
            for (int mt = 0; mt < 2; ++mt) {
                acc[mt][th][0] = __builtin_amdgcn_mfma_f32_16x16x32_bf16(a[mt][0], bi, acc[mt][th][0], 0, 0, 0);
                acc[mt][th][1] = __builtin_amdgcn_mfma_f32_16x16x32_bf16(a[mt][1], bh, acc[mt][th][1], 0, 0, 0);
            }
        }
    }
    __syncthreads();   // Xb dead -> Hn overlay safe

    // ---- gate math; lane holds (m = mt*16 + gq*4 + r, d = 16w + c) ----
    const int d = w * 16 + c;
    const float bs_r = b_ih[d]       + b_hh[d];
    const float bs_z = b_ih[d + 128] + b_hh[d + 128];
    const float bi_n = b_ih[d + 256];
    const float bh_n = b_hh[d + 256];

    #pragma unroll
    for (int mt = 0; mt < 2; ++mt) {
        #pragma unroll
        for (int r = 0; r < 4; ++r) {
            const int m = mt * 16 + gq * 4 + r;
            float s_r  = acc[mt][0][0][r] + acc[mt][0][1][r] + bs_r;
            float s_z  = acc[mt][1][0][r] + acc[mt][1][1][r] + bs_z;
            float gi_n = acc[mt][2][0][r] + bi_n;
            float gh_n = acc[mt][2][1][r] + bh_n;
            float rg = 1.f / (1.f + __expf(-s_r));
            float zg = 1.f / (1.f + __expf(-s_z));
            float aa = gi_n + rg * gh_n;
            float n  = 1.f - 2.f / (__expf(2.f * aa) + 1.f);   // tanh, inf-safe
            float h  = bf2f(Hb[m][d]);
            Hn[m][d] = f2bf((1.f - zg) * n + zg * h);
        }
    }
    __syncthreads();

    // ---- epilogue: LDS reads, sequential coalesced stores ----
    #pragma unroll
    for (int jj = 0; jj < 2; ++jj) {
        int j = t + jj * 512;
        int row = j >> 5, c4 = j & 31;
        if (rinfo[row] < 0) continue;                  // copied at stage
        size_t off = (size_t)(rb + row) * DIM + c4 * 4;
        short4_t hns = *(short4_t*)&Hn[row][c4 * 4];
        short4_t hs  = *(short4_t*)&Hb[row][c4 * 4];
        short4_t vs  = *(short4_t*)&Vb[row][c4 * 4];
        f32x4 hn, var;
        hn.x = bf2f(hns.x); hn.y = bf2f(hns.y); hn.z = bf2f(hns.z); hn.w = bf2f(hns.w);
        float dx = hn.x - bf2f(hs.x), dy = hn.y - bf2f(hs.y);
        float dz = hn.z - bf2f(hs.z), dw = hn.w - bf2f(hs.w);
        var.x = 0.9f * bf2f(vs.x) + 0.1f * dx * dx;
        var.y = 0.9f * bf2f(vs.y) + 0.1f * dy * dy;
        var.z = 0.9f * bf2f(vs.z) + 0.1f * dz * dz;
        var.w = 0.9f * bf2f(vs.w) + 0.1f * dw * dw;
        *(f32x4*)(out0 + off) = hn;
        *(f32x4*)(out1 + off) = var;
    }
}

// ----------------------------------------------- fallback: R5 structure ----
__global__ void __launch_bounds__(256)
k_copy(const float* __restrict__ hidden,
       const float* __restrict__ variance,
       const unsigned char* __restrict__ mask,   // null -> copy all
       float* __restrict__ out0,
       float* __restrict__ out1) {
    int gid = blockIdx.x * 256 + threadIdx.x;
    int row = gid >> 4;
    int c8  = gid & 15;
    if (mask && mask[row]) return;
    size_t off = (size_t)row * DIM + c8 * 8;
    f32x4 a0 = *(const f32x4*)(hidden + off);
    f32x4 a1 = *(const f32x4*)(hidden + off + 4);
    f32x4 b0 = *(const f32x4*)(variance + off);
    f32x4 b1 = *(const f32x4*)(variance + off + 4);
    *(f32x4*)(out0 + off)     = a0;
    *(f32x4*)(out0 + off + 4) = a1;
    *(f32x4*)(out1 + off)     = b0;
    *(f32x4*)(out1 + off + 4) = b1;
}

__global__ void __launch_bounds__(512)
k_gru(const float* __restrict__ hidden,
      const float* __restrict__ variance,
      const int*   __restrict__ idx,
      const float* __restrict__ xg,
      const short* __restrict__ WbIH,
      const short* __restrict__ WbHH,
      const float* __restrict__ b_ih,
      const float* __restrict__ b_hh,
      float* __restrict__ out0,
      float* __restrict__ out1) {
    __shared__ __align__(16) char smem[26112];
    short (*Xb)[136] = (short(*)[136])smem;
    short (*Hb)[136] = (short(*)[136])(smem + 8704);
    short (*Vb)[136] = (short(*)[136])(smem + 17408);
    short (*Hn)[136] = (short(*)[136])smem;

    const int t  = threadIdx.x;
    const int rb = blockIdx.x * 32;

    #pragma unroll
    for (int jj = 0; jj < 2; ++jj) {
        int j = t + jj * 512;
        int row = j >> 5, c4 = j & 31;
        int node = idx[rb + row];
        f32x4 xv = *(const f32x4*)(xg + (size_t)(rb + row) * DIM + c4 * 4);
        f32x4 hv = *(const f32x4*)(hidden + (size_t)node * DIM + c4 * 4);
        f32x4 vv = *(const f32x4*)(variance + (size_t)node * DIM + c4 * 4);
        short4_t xs, hs, vs;
        xs.x = f2bf(xv.x); xs.y = f2bf(xv.y); xs.z = f2bf(xv.z); xs.w = f2bf(xv.w);
        hs.x = f2bf(hv.x); hs.y = f2bf(hv.y); hs.z = f2bf(hv.z); hs.w = f2bf(hv.w);
        vs.x = f2bf(vv.x); vs.y = f2bf(vv.y); vs.z = f2bf(vv.z); vs.w = f2bf(vv.w);
        *(short4_t*)&Xb[row][c4 * 4] = xs;
        *(short4_t*)&Hb[row][c4 * 4] = hs;
        *(short4_t*)&Vb[row][c4 * 4] = vs;
    }
    __syncthreads();

    const int w  = t >> 6;
    const int l  = t & 63;
    const int c  = l & 15;
    const int gq = l >> 4;

    f32x4 acc[2][3][2] = {};
    #pragma unroll
    for (int ks = 0; ks < 4; ++ks) {
        const int k0 = ks * 32 + gq * 8;
        short8 a[2][2];
        a[0][0] = *(const short8*)&Xb[c][k0];
        a[1][0] = *(const short8*)&Xb[16 + c][k0];
        a[0][1] = *(const short8*)&Hb[c][k0];
        a[1][1] = *(const short8*)&Hb[16 + c][k0];
        #pragma unroll
        for (int th = 0; th < 3; ++th) {
            const int o = w * 16 + th * 128 + c;
            const short8 bi = *(const short8*)(WbIH + (size_t)o * DIM + k0);
            const short8 bh = *(const short8*)(WbHH + (size_t)o * DIM + k0);
            #pragma unroll
            for (int mt = 0; mt < 2; ++mt) {
                acc[mt][th][0] = __builtin_amdgcn_mfma_f32_16x16x32_bf16(a[mt][0], bi, acc[mt][th][0], 0, 0, 0);
                acc[mt][th][1] = __builtin_amdgcn_mfma_f32_16x16x32_bf16(a[mt][1], bh, acc[mt][th][1], 0, 0, 0);
            }
        }
    }
    __syncthreads();

    const int d = w * 16 + c;
    const float bs_r = b_ih[d]       + b_hh[d];
    const float bs_z = b_ih[d + 128] + b_hh[d + 128];
    const float bi_n = b_ih[d + 256];
    const float bh_n = b_hh[d + 256];
    #pragma unroll
    for (int mt = 0; mt < 2; ++mt) {
        #pragma unroll
        for (int r = 0; r < 4; ++r) {
            const int m = mt * 16 + gq * 4 + r;
            float s_r  = acc[mt][0][0][r] + acc[mt][0][1][r] + bs_r;
            float s_z  = acc[mt][1][0][r] + acc[mt][1][1][r] + bs_z;
            float gi_n = acc[mt][2][0][r] + bi_n;
            float gh_n = acc[mt][2][1][r] + bh_n;
            float rg = 1.f / (1.f + __expf(-s_r));
            float zg = 1.f / (1.f + __expf(-s_z));
            float aa = gi_n + rg * gh_n;
            float n  = 1.f - 2.f / (__expf(2.f * aa) + 1.f);
            float h  = bf2f(Hb[m][d]);
            Hn[m][d] = f2bf((1.f - zg) * n + zg * h);
        }
    }
    __syncthreads();

    #pragma unroll
    for (int jj = 0; jj < 2; ++jj) {
        int j = t + jj * 512;
        int row = j >> 5, c4 = j & 31;
        int node = idx[rb + row];
        size_t off = (size_t)node * DIM + c4 * 4;
        short4_t hns = *(short4_t*)&Hn[row][c4 * 4];
        short4_t hs  = *(short4_t*)&Hb[row][c4 * 4];
        short4_t vs  = *(short4_t*)&Vb[row][c4 * 4];
        f32x4 hn, var;
        hn.x = bf2f(hns.x); hn.y = bf2f(hns.y); hn.z = bf2f(hns.z); hn.w = bf2f(hns.w);
        float dx = hn.x - bf2f(hs.x), dy = hn.y - bf2f(hs.y);
        float dz = hn.z - bf2f(hs.z), dw = hn.w - bf2f(hs.w);
        var.x = 0.9f * bf2f(vs.x) + 0.1f * dx * dx;
        var.y = 0.9f * bf2f(vs.y) + 0.1f * dy * dy;
        var.z = 0.9f * bf2f(vs.z) + 0.1f * dz * dz;
        var.w = 0.9f * bf2f(vs.w) + 0.1f * dw * dw;
        *(f32x4*)(out0 + off) = hn;
        *(f32x4*)(out1 + off) = var;
    }
}

// -------------------------------------------------------------- launch ----
extern "C" void kernel_launch(void* const* d_in, const int* in_sizes, int n_in,
                              void* d_out, int out_size, void* d_ws, size_t ws_size,
                              hipStream_t stream) {
    const float* hidden   = (const float*)d_in[0];
    const float* variance = (const float*)d_in[1];
    const int*   idx      = (const int*)d_in[2];
    const float* x        = (const float*)d_in[3];
    const float* Wih      = (const float*)d_in[4];
    const float* Whh      = (const float*)d_in[5];
    const float* bih      = (const float*)d_in[6];
    const float* bhh      = (const float*)d_in[7];
    float* out0 = (float*)d_out;
    float* out1 = out0 + (size_t)NUM_NODES * DIM;

    const size_t invB  = (size_t)NUM_NODES * 4;          // 2,000,000
    const size_t maskB = (size_t)NUM_NODES;              // 500,000
    const size_t wB    = (size_t)3 * DIM * DIM * 2;      // 196,608 per matrix

    const bool full = ws_size >= invB + 2 * wB;          // streaming path
    const bool mid  = !full && ws_size >= maskB + 16 + 2 * wB;

    if (full) {
        int*   inv  = (int*)d_ws;
        short* WbIH = (short*)((char*)d_ws + invB);      // invB % 16 == 0
        short* WbHH = WbIH + 3 * DIM * DIM;
        k_init<<<(NUM_NODES + 255) / 256, 256, 0, stream>>>(
            inv, nullptr, Wih, Whh, WbIH, WbHH);
        k_scatter<<<BATCH / 256, 256, 0, stream>>>(inv, nullptr, idx);
        k_stream<<<NBLK, 512, 0, stream>>>(hidden, variance, inv, x,
                                           WbIH, WbHH, bih, bhh, out0, out1);
    } else if (mid) {
        unsigned char* mask = (unsigned char*)d_ws;
        short* WbIH = (short*)((char*)d_ws + ((maskB + 15) & ~size_t(15)));
        short* WbHH = WbIH + 3 * DIM * DIM;
        k_init<<<(NUM_NODES + 255) / 256, 256, 0, stream>>>(
            nullptr, mask, Wih, Whh, WbIH, WbHH);
        k_scatter<<<BATCH / 256, 256, 0, stream>>>(nullptr, mask, idx);
        k_copy<<<(NUM_NODES * 16) / 256, 256, 0, stream>>>(
            hidden, variance, mask, out0, out1);
        k_gru<<<BATCH / 32, 512, 0, stream>>>(hidden, variance, idx, x,
                                              WbIH, WbHH, bih, bhh, out0, out1);
    } else {
        short* WbIH = (short*)d_ws;
        short* WbHH = WbIH + 3 * DIM * DIM;
        k_init<<<(NUM_NODES + 255) / 256, 256, 0, stream>>>(
            nullptr, nullptr, Wih, Whh, WbIH, WbHH);
        k_copy<<<(NUM_NODES * 16) / 256, 256, 0, stream>>>(
            hidden, variance, nullptr, out0, out1);
        k_gru<<<BATCH / 32, 512, 0, stream>>>(hidden, variance, idx, x,
                                              WbIH, WbHH, bih, bhh, out0, out1);
    }
}

// Round 13
// 257.232 us; speedup vs baseline: 1.5185x; 1.0391x over previous
//
#include <hip/hip_runtime.h>
#include <hip/hip_bf16.h>
#include <cstdint>
#include <cstddef>

#define NUM_NODES 500000
#define DIM 128
#define BATCH 131072
#define NBLK (NUM_NODES / 32)     // 15625 exactly

typedef __attribute__((ext_vector_type(8))) short short8;
typedef __attribute__((ext_vector_type(4))) short short4_t;
typedef __attribute__((ext_vector_type(4))) float f32x4;

static __device__ __forceinline__ short f2bf(float f) {
    unsigned u = __builtin_bit_cast(unsigned, f);
    u += 0x7fffu + ((u >> 16) & 1u);   // round-to-nearest-even
    return (short)(u >> 16);
}
static __device__ __forceinline__ float bf2f(short s) {
    unsigned u = ((unsigned)(unsigned short)s) << 16;
    return __builtin_bit_cast(float, u);
}

// ---------------------------------------------------------------- init ----
__global__ void k_init(int* __restrict__ inv,            // may be null
                       unsigned char* __restrict__ mask, // may be null
                       const float* __restrict__ Wih,
                       const float* __restrict__ Whh,
                       short* __restrict__ WbIH,
                       short* __restrict__ WbHH) {
    int i = blockIdx.x * blockDim.x + threadIdx.x;
    if (i < NUM_NODES) {
        if (inv)  inv[i] = -1;
        if (mask) mask[i] = 0;
    }
    if (i < 3 * DIM * DIM) {
        WbIH[i] = f2bf(Wih[i]);
        WbHH[i] = f2bf(Whh[i]);
    }
}

__global__ void k_scatter(int* __restrict__ inv, unsigned char* __restrict__ mask,
                          const int* __restrict__ idx) {
    int i = blockIdx.x * blockDim.x + threadIdx.x;
    if (i < BATCH) {
        int n = idx[i];
        if (inv)  inv[n] = i;
        if (mask) mask[n] = 1;
    }
}

// --------------------------------------------------------------- stream ----
// ONE kernel over all rows, 512 thr = 8 waves, 32 sequential rows/block.
// R13 change: blockIdx remapped by coprime stride so update blocks (which
// cluster at low node ids for arange idx) INTERLEAVE with copy blocks ->
// update-block latency hides under the copy stream's BW.
__global__ void __launch_bounds__(512)
k_stream(const float* __restrict__ hidden,
         const float* __restrict__ variance,
         const int*   __restrict__ inv,
         const float* __restrict__ xg,
         const short* __restrict__ WbIH,     // [384][128] bf16 bits
         const short* __restrict__ WbHH,
         const float* __restrict__ b_ih,
         const float* __restrict__ b_hh,
         float* __restrict__ out0,
         float* __restrict__ out1) {
    __shared__ __align__(16) char smem[26112];
    short (*Xb)[136] = (short(*)[136])smem;             // bf16 x tile
    short (*Hb)[136] = (short(*)[136])(smem + 8704);    // bf16 h tile
    short (*Vb)[136] = (short(*)[136])(smem + 17408);   // bf16 variance tile
    short (*Hn)[136] = (short(*)[136])smem;             // bf16 h_new, overlays Xb
    __shared__ int rinfo[32];
    __shared__ int hasUpd;

    const int t  = threadIdx.x;
    // bijective spread: 15625 = 5^6, gcd(4099,5)=1
    const int pb = (int)(((unsigned)blockIdx.x * 4099u) % 15625u);
    const int rb = pb * 32;

    if (t == 0) hasUpd = 0;
    if (t < 32) rinfo[t] = inv[rb + t];
    __syncthreads();
    if (t < 32 && rinfo[t] >= 0) hasUpd = 1;
    __syncthreads();

    if (!hasUpd) {
        // ---- pure copy: fully sequential streaming ----
        #pragma unroll
        for (int jj = 0; jj < 2; ++jj) {
            int j = t + jj * 512;
            size_t off = (size_t)rb * DIM + j * 4;      // rows sequential
            f32x4 h = *(const f32x4*)(hidden + off);
            f32x4 v = *(const f32x4*)(variance + off);
            *(f32x4*)(out0 + off) = h;
            *(f32x4*)(out1 + off) = v;
        }
        return;
    }

    // ---- stage: local h/var + inv-gathered x; copy-out non-updated rows ----
    #pragma unroll
    for (int jj = 0; jj < 2; ++jj) {
        int j = t + jj * 512;
        int row = j >> 5, c4 = j & 31;
        size_t off = (size_t)(rb + row) * DIM + c4 * 4;
        f32x4 hv = *(const f32x4*)(hidden + off);
        f32x4 vv = *(const f32x4*)(variance + off);
        int iv = rinfo[row];
        f32x4 xv = {0.f, 0.f, 0.f, 0.f};
        if (iv >= 0) {
            xv = *(const f32x4*)(xg + (size_t)iv * DIM + c4 * 4);
        } else {
            *(f32x4*)(out0 + off) = hv;                 // mixed block: copy now
            *(f32x4*)(out1 + off) = vv;
        }
        short4_t xs, hs, vs;
        xs.x = f2bf(xv.x); xs.y = f2bf(xv.y); xs.z = f2bf(xv.z); xs.w = f2bf(xv.w);
        hs.x = f2bf(hv.x); hs.y = f2bf(hv.y); hs.z = f2bf(hv.z); hs.w = f2bf(hv.w);
        vs.x = f2bf(vv.x); vs.y = f2bf(vv.y); vs.z = f2bf(vv.z); vs.w = f2bf(vv.w);
        *(short4_t*)&Xb[row][c4 * 4] = xs;
        *(short4_t*)&Hb[row][c4 * 4] = hs;
        *(short4_t*)&Vb[row][c4 * 4] = vs;
    }
    __syncthreads();

    const int w  = t >> 6;       // wave id 0..7 -> output dims 16w..16w+15
    const int l  = t & 63;
    const int c  = l & 15;
    const int gq = l >> 4;

    f32x4 acc[2][3][2] = {};     // [m-tile][gate third][0=x@Wih 1=h@Whh]

    #pragma unroll
    for (int ks = 0; ks < 4; ++ks) {
        const int k0 = ks * 32 + gq * 8;
        short8 a[2][2];
        a[0][0] = *(const short8*)&Xb[c][k0];
        a[1][0] = *(const short8*)&Xb[16 + c][k0];
        a[0][1] = *(const short8*)&Hb[c][k0];
        a[1][1] = *(const short8*)&Hb[16 + c][k0];
        #pragma unroll
        for (int th = 0; th < 3; ++th) {
            const int o = w * 16 + th * 128 + c;        // gate output row of W
            const short8 bi = *(const short8*)(WbIH + (size_t)o * DIM + k0);
            const short8 bh = *(const short8*)(WbHH + (size_t)o * DIM + k0);
            #pragma unroll
            for (int mt = 0; mt < 2; ++mt) {
                acc[mt][th][0] = __builtin_amdgcn_mfma_f32_16x16x32_bf16(a[mt][0], bi, acc[mt][th][0], 0, 0, 0);
                acc[mt][th][1] = __builtin_amdgcn_mfma_f32_16x16x32_bf16(a[mt][1], bh, acc[mt][th][1], 0, 0, 0);
            }
        }
    }
    __syncthreads();   // Xb dead -> Hn overlay safe

    // ---- gate math; lane holds (m = mt*16 + gq*4 + r, d = 16w + c) ----
    const int d = w * 16 + c;
    const float bs_r = b_ih[d]       + b_hh[d];
    const float bs_z = b_ih[d + 128] + b_hh[d + 128];
    const float bi_n = b_ih[d + 256];
    const float bh_n = b_hh[d + 256];

    #pragma unroll
    for (int mt = 0; mt < 2; ++mt) {
        #pragma unroll
        for (int r = 0; r < 4; ++r) {
            const int m = mt * 16 + gq * 4 + r;
            float s_r  = acc[mt][0][0][r] + acc[mt][0][1][r] + bs_r;
            float s_z  = acc[mt][1][0][r] + acc[mt][1][1][r] + bs_z;
            float gi_n = acc[mt][2][0][r] + bi_n;
            float gh_n = acc[mt][2][1][r] + bh_n;
            float rg = 1.f / (1.f + __expf(-s_r));
            float zg = 1.f / (1.f + __expf(-s_z));
            float aa = gi_n + rg * gh_n;
            float n  = 1.f - 2.f / (__expf(2.f * aa) + 1.f);   // tanh, inf-safe
            float h  = bf2f(Hb[m][d]);
            Hn[m][d] = f2bf((1.f - zg) * n + zg * h);
        }
    }
    __syncthreads();

    // ---- epilogue: LDS reads, sequential coalesced stores ----
    #pragma unroll
    for (int jj = 0; jj < 2; ++jj) {
        int j = t + jj * 512;
        int row = j >> 5, c4 = j & 31;
        if (rinfo[row] < 0) continue;                  // copied at stage
        size_t off = (size_t)(rb + row) * DIM + c4 * 4;
        short4_t hns = *(short4_t*)&Hn[row][c4 * 4];
        short4_t hs  = *(short4_t*)&Hb[row][c4 * 4];
        short4_t vs  = *(short4_t*)&Vb[row][c4 * 4];
        f32x4 hn, var;
        hn.x = bf2f(hns.x); hn.y = bf2f(hns.y); hn.z = bf2f(hns.z); hn.w = bf2f(hns.w);
        float dx = hn.x - bf2f(hs.x), dy = hn.y - bf2f(hs.y);
        float dz = hn.z - bf2f(hs.z), dw = hn.w - bf2f(hs.w);
        var.x = 0.9f * bf2f(vs.x) + 0.1f * dx * dx;
        var.y = 0.9f * bf2f(vs.y) + 0.1f * dy * dy;
        var.z = 0.9f * bf2f(vs.z) + 0.1f * dz * dz;
        var.w = 0.9f * bf2f(vs.w) + 0.1f * dw * dw;
        *(f32x4*)(out0 + off) = hn;
        *(f32x4*)(out1 + off) = var;
    }
}

// ----------------------------------------------- fallback: R5 structure ----
__global__ void __launch_bounds__(256)
k_copy(const float* __restrict__ hidden,
       const float* __restrict__ variance,
       const unsigned char* __restrict__ mask,   // null -> copy all
       float* __restrict__ out0,
       float* __restrict__ out1) {
    int gid = blockIdx.x * 256 + threadIdx.x;
    int row = gid >> 4;
    int c8  = gid & 15;
    if (mask && mask[row]) return;
    size_t off = (size_t)row * DIM + c8 * 8;
    f32x4 a0 = *(const f32x4*)(hidden + off);
    f32x4 a1 = *(const f32x4*)(hidden + off + 4);
    f32x4 b0 = *(const f32x4*)(variance + off);
    f32x4 b1 = *(const f32x4*)(variance + off + 4);
    *(f32x4*)(out0 + off)     = a0;
    *(f32x4*)(out0 + off + 4) = a1;
    *(f32x4*)(out1 + off)     = b0;
    *(f32x4*)(out1 + off + 4) = b1;
}

__global__ void __launch_bounds__(512)
k_gru(const float* __restrict__ hidden,
      const float* __restrict__ variance,
      const int*   __restrict__ idx,
      const float* __restrict__ xg,
      const short* __restrict__ WbIH,
      const short* __restrict__ WbHH,
      const float* __restrict__ b_ih,
      const float* __restrict__ b_hh,
      float* __restrict__ out0,
      float* __restrict__ out1) {
    __shared__ __align__(16) char smem[26112];
    short (*Xb)[136] = (short(*)[136])smem;
    short (*Hb)[136] = (short(*)[136])(smem + 8704);
    short (*Vb)[136] = (short(*)[136])(smem + 17408);
    short (*Hn)[136] = (short(*)[136])smem;

    const int t  = threadIdx.x;
    const int rb = blockIdx.x * 32;

    #pragma unroll
    for (int jj = 0; jj < 2; ++jj) {
        int j = t + jj * 512;
        int row = j >> 5, c4 = j & 31;
        int node = idx[rb + row];
        f32x4 xv = *(const f32x4*)(xg + (size_t)(rb + row) * DIM + c4 * 4);
        f32x4 hv = *(const f32x4*)(hidden + (size_t)node * DIM + c4 * 4);
        f32x4 vv = *(const f32x4*)(variance + (size_t)node * DIM + c4 * 4);
        short4_t xs, hs, vs;
        xs.x = f2bf(xv.x); xs.y = f2bf(xv.y); xs.z = f2bf(xv.z); xs.w = f2bf(xv.w);
        hs.x = f2bf(hv.x); hs.y = f2bf(hv.y); hs.z = f2bf(hv.z); hs.w = f2bf(hv.w);
        vs.x = f2bf(vv.x); vs.y = f2bf(vv.y); vs.z = f2bf(vv.z); vs.w = f2bf(vv.w);
        *(short4_t*)&Xb[row][c4 * 4] = xs;
        *(short4_t*)&Hb[row][c4 * 4] = hs;
        *(short4_t*)&Vb[row][c4 * 4] = vs;
    }
    __syncthreads();

    const int w  = t >> 6;
    const int l  = t & 63;
    const int c  = l & 15;
    const int gq = l >> 4;

    f32x4 acc[2][3][2] = {};
    #pragma unroll
    for (int ks = 0; ks < 4; ++ks) {
        const int k0 = ks * 32 + gq * 8;
        short8 a[2][2];
        a[0][0] = *(const short8*)&Xb[c][k0];
        a[1][0] = *(const short8*)&Xb[16 + c][k0];
        a[0][1] = *(const short8*)&Hb[c][k0];
        a[1][1] = *(const short8*)&Hb[16 + c][k0];
        #pragma unroll
        for (int th = 0; th < 3; ++th) {
            const int o = w * 16 + th * 128 + c;
            const short8 bi = *(const short8*)(WbIH + (size_t)o * DIM + k0);
            const short8 bh = *(const short8*)(WbHH + (size_t)o * DIM + k0);
            #pragma unroll
            for (int mt = 0; mt < 2; ++mt) {
                acc[mt][th][0] = __builtin_amdgcn_mfma_f32_16x16x32_bf16(a[mt][0], bi, acc[mt][th][0], 0, 0, 0);
                acc[mt][th][1] = __builtin_amdgcn_mfma_f32_16x16x32_bf16(a[mt][1], bh, acc[mt][th][1], 0, 0, 0);
            }
        }
    }
    __syncthreads();

    const int d = w * 16 + c;
    const float bs_r = b_ih[d]       + b_hh[d];
    const float bs_z = b_ih[d + 128] + b_hh[d + 128];
    const float bi_n = b_ih[d + 256];
    const float bh_n = b_hh[d + 256];
    #pragma unroll
    for (int mt = 0; mt < 2; ++mt) {
        #pragma unroll
        for (int r = 0; r < 4; ++r) {
            const int m = mt * 16 + gq * 4 + r;
            float s_r  = acc[mt][0][0][r] + acc[mt][0][1][r] + bs_r;
            float s_z  = acc[mt][1][0][r] + acc[mt][1][1][r] + bs_z;
            float gi_n = acc[mt][2][0][r] + bi_n;
            float gh_n = acc[mt][2][1][r] + bh_n;
            float rg = 1.f / (1.f + __expf(-s_r));
            float zg = 1.f / (1.f + __expf(-s_z));
            float aa = gi_n + rg * gh_n;
            float n  = 1.f - 2.f / (__expf(2.f * aa) + 1.f);
            float h  = bf2f(Hb[m][d]);
            Hn[m][d] = f2bf((1.f - zg) * n + zg * h);
        }
    }
    __syncthreads();

    #pragma unroll
    for (int jj = 0; jj < 2; ++jj) {
        int j = t + jj * 512;
        int row = j >> 5, c4 = j & 31;
        int node = idx[rb + row];
        size_t off = (size_t)node * DIM + c4 * 4;
        short4_t hns = *(short4_t*)&Hn[row][c4 * 4];
        short4_t hs  = *(short4_t*)&Hb[row][c4 * 4];
        short4_t vs  = *(short4_t*)&Vb[row][c4 * 4];
        f32x4 hn, var;
        hn.x = bf2f(hns.x); hn.y = bf2f(hns.y); hn.z = bf2f(hns.z); hn.w = bf2f(hns.w);
        float dx = hn.x - bf2f(hs.x), dy = hn.y - bf2f(hs.y);
        float dz = hn.z - bf2f(hs.z), dw = hn.w - bf2f(hs.w);
        var.x = 0.9f * bf2f(vs.x) + 0.1f * dx * dx;
        var.y = 0.9f * bf2f(vs.y) + 0.1f * dy * dy;
        var.z = 0.9f * bf2f(vs.z) + 0.1f * dz * dz;
        var.w = 0.9f * bf2f(vs.w) + 0.1f * dw * dw;
        *(f32x4*)(out0 + off) = hn;
        *(f32x4*)(out1 + off) = var;
    }
}

// -------------------------------------------------------------- launch ----
extern "C" void kernel_launch(void* const* d_in, const int* in_sizes, int n_in,
                              void* d_out, int out_size, void* d_ws, size_t ws_size,
                              hipStream_t stream) {
    const float* hidden   = (const float*)d_in[0];
    const float* variance = (const float*)d_in[1];
    const int*   idx      = (const int*)d_in[2];
    const float* x        = (const float*)d_in[3];
    const float* Wih      = (const float*)d_in[4];
    const float* Whh      = (const float*)d_in[5];
    const float* bih      = (const float*)d_in[6];
    const float* bhh      = (const float*)d_in[7];
    float* out0 = (float*)d_out;
    float* out1 = out0 + (size_t)NUM_NODES * DIM;

    const size_t invB  = (size_t)NUM_NODES * 4;          // 2,000,000
    const size_t maskB = (size_t)NUM_NODES;              // 500,000
    const size_t wB    = (size_t)3 * DIM * DIM * 2;      // 196,608 per matrix

    const bool full = ws_size >= invB + 2 * wB;          // streaming path
    const bool mid  = !full && ws_size >= maskB + 16 + 2 * wB;

    if (full) {
        int*   inv  = (int*)d_ws;
        short* WbIH = (short*)((char*)d_ws + invB);      // invB % 16 == 0
        short* WbHH = WbIH + 3 * DIM * DIM;
        k_init<<<(NUM_NODES + 255) / 256, 256, 0, stream>>>(
            inv, nullptr, Wih, Whh, WbIH, WbHH);
        k_scatter<<<BATCH / 256, 256, 0, stream>>>(inv, nullptr, idx);
        k_stream<<<NBLK, 512, 0, stream>>>(hidden, variance, inv, x,
                                           WbIH, WbHH, bih, bhh, out0, out1);
    } else if (mid) {
        unsigned char* mask = (unsigned char*)d_ws;
        short* WbIH = (short*)((char*)d_ws + ((maskB + 15) & ~size_t(15)));
        short* WbHH = WbIH + 3 * DIM * DIM;
        k_init<<<(NUM_NODES + 255) / 256, 256, 0, stream>>>(
            nullptr, mask, Wih, Whh, WbIH, WbHH);
        k_scatter<<<BATCH / 256, 256, 0, stream>>>(nullptr, mask, idx);
        k_copy<<<(NUM_NODES * 16) / 256, 256, 0, stream>>>(
            hidden, variance, mask, out0, out1);
        k_gru<<<BATCH / 32, 512, 0, stream>>>(hidden, variance, idx, x,
                                              WbIH, WbHH, bih, bhh, out0, out1);
    } else {
        short* WbIH = (short*)d_ws;
        short* WbHH = WbIH + 3 * DIM * DIM;
        k_init<<<(NUM_NODES + 255) / 256, 256, 0, stream>>>(
            nullptr, nullptr, Wih, Whh, WbIH, WbHH);
        k_copy<<<(NUM_NODES * 16) / 256, 256, 0, stream>>>(
            hidden, variance, nullptr, out0, out1);
        k_gru<<<BATCH / 32, 512, 0, stream>>>(hidden, variance, idx, x,
                                              WbIH, WbHH, bih, bhh, out0, out1);
    }
}

// Round 14
// 253.244 us; speedup vs baseline: 1.5424x; 1.0157x over previous
//
#include <hip/hip_runtime.h>
#include <hip/hip_bf16.h>
#include <cstdint>
#include <cstddef>

#define NUM_NODES 500000
#define DIM 128
#define BATCH 131072
#define NBLK (NUM_NODES / 32)     // 15625 exactly

typedef __attribute__((ext_vector_type(8))) short short8;
typedef __attribute__((ext_vector_type(4))) short short4_t;
typedef __attribute__((ext_vector_type(4))) float f32x4;

static __device__ __forceinline__ short f2bf(float f) {
    unsigned u = __builtin_bit_cast(unsigned, f);
    u += 0x7fffu + ((u >> 16) & 1u);   // round-to-nearest-even
    return (short)(u >> 16);
}
static __device__ __forceinline__ float bf2f(short s) {
    unsigned u = ((unsigned)(unsigned short)s) << 16;
    return __builtin_bit_cast(float, u);
}
static __device__ __forceinline__ f32x4 ntl(const float* p) {
    return __builtin_nontemporal_load((const f32x4*)p);
}
static __device__ __forceinline__ void nts(float* p, f32x4 v) {
    __builtin_nontemporal_store(v, (f32x4*)p);
}

// ---------------------------------------------------------------- init ----
__global__ void k_init(int* __restrict__ inv,            // may be null
                       unsigned char* __restrict__ mask, // may be null
                       const float* __restrict__ Wih,
                       const float* __restrict__ Whh,
                       short* __restrict__ WbIH,
                       short* __restrict__ WbHH) {
    int i = blockIdx.x * blockDim.x + threadIdx.x;
    if (i < NUM_NODES) {
        if (inv)  inv[i] = -1;
        if (mask) mask[i] = 0;
    }
    if (i < 3 * DIM * DIM) {
        WbIH[i] = f2bf(Wih[i]);
        WbHH[i] = f2bf(Whh[i]);
    }
}

__global__ void k_scatter(int* __restrict__ inv, unsigned char* __restrict__ mask,
                          const int* __restrict__ idx) {
    int i = blockIdx.x * blockDim.x + threadIdx.x;
    if (i < BATCH) {
        int n = idx[i];
        if (inv)  inv[n] = i;
        if (mask) mask[n] = 1;
    }
}

// --------------------------------------------------------------- stream ----
// R14 change vs R13 (single variable): ALL streaming traffic (copy loads/
// stores, h/var/x stage reads, epilogue stores) is NONTEMPORAL so it doesn't
// evict the L2-resident W matrices that every update block re-streams.
// W loads stay cached. Block permutation + structure identical to R13.
__global__ void __launch_bounds__(512)
k_stream(const float* __restrict__ hidden,
         const float* __restrict__ variance,
         const int*   __restrict__ inv,
         const float* __restrict__ xg,
         const short* __restrict__ WbIH,     // [384][128] bf16 bits
         const short* __restrict__ WbHH,
         const float* __restrict__ b_ih,
         const float* __restrict__ b_hh,
         float* __restrict__ out0,
         float* __restrict__ out1) {
    __shared__ __align__(16) char smem[26112];
    short (*Xb)[136] = (short(*)[136])smem;             // bf16 x tile
    short (*Hb)[136] = (short(*)[136])(smem + 8704);    // bf16 h tile
    short (*Vb)[136] = (short(*)[136])(smem + 17408);   // bf16 variance tile
    short (*Hn)[136] = (short(*)[136])smem;             // bf16 h_new, overlays Xb
    __shared__ int rinfo[32];
    __shared__ int hasUpd;

    const int t  = threadIdx.x;
    // bijective spread: 15625 = 5^6, gcd(4099,5)=1
    const int pb = (int)(((unsigned)blockIdx.x * 4099u) % 15625u);
    const int rb = pb * 32;

    if (t == 0) hasUpd = 0;
    if (t < 32) rinfo[t] = inv[rb + t];
    __syncthreads();
    if (t < 32 && rinfo[t] >= 0) hasUpd = 1;
    __syncthreads();

    if (!hasUpd) {
        // ---- pure copy: fully sequential streaming (nontemporal) ----
        #pragma unroll
        for (int jj = 0; jj < 2; ++jj) {
            int j = t + jj * 512;
            size_t off = (size_t)rb * DIM + j * 4;      // rows sequential
            f32x4 h = ntl(hidden + off);
            f32x4 v = ntl(variance + off);
            nts(out0 + off, h);
            nts(out1 + off, v);
        }
        return;
    }

    // ---- stage: local h/var + inv-gathered x; copy-out non-updated rows ----
    #pragma unroll
    for (int jj = 0; jj < 2; ++jj) {
        int j = t + jj * 512;
        int row = j >> 5, c4 = j & 31;
        size_t off = (size_t)(rb + row) * DIM + c4 * 4;
        f32x4 hv = ntl(hidden + off);
        f32x4 vv = ntl(variance + off);
        int iv = rinfo[row];
        f32x4 xv = {0.f, 0.f, 0.f, 0.f};
        if (iv >= 0) {
            xv = ntl(xg + (size_t)iv * DIM + c4 * 4);
        } else {
            nts(out0 + off, hv);                        // mixed block: copy now
            nts(out1 + off, vv);
        }
        short4_t xs, hs, vs;
        xs.x = f2bf(xv.x); xs.y = f2bf(xv.y); xs.z = f2bf(xv.z); xs.w = f2bf(xv.w);
        hs.x = f2bf(hv.x); hs.y = f2bf(hv.y); hs.z = f2bf(hv.z); hs.w = f2bf(hv.w);
        vs.x = f2bf(vv.x); vs.y = f2bf(vv.y); vs.z = f2bf(vv.z); vs.w = f2bf(vv.w);
        *(short4_t*)&Xb[row][c4 * 4] = xs;
        *(short4_t*)&Hb[row][c4 * 4] = hs;
        *(short4_t*)&Vb[row][c4 * 4] = vs;
    }
    __syncthreads();

    const int w  = t >> 6;       // wave id 0..7 -> output dims 16w..16w+15
    const int l  = t & 63;
    const int c  = l & 15;
    const int gq = l >> 4;

    f32x4 acc[2][3][2] = {};     // [m-tile][gate third][0=x@Wih 1=h@Whh]

    #pragma unroll
    for (int ks = 0; ks < 4; ++ks) {
        const int k0 = ks * 32 + gq * 8;
        short8 a[2][2];
        a[0][0] = *(const short8*)&Xb[c][k0];
        a[1][0] = *(const short8*)&Xb[16 + c][k0];
        a[0][1] = *(const short8*)&Hb[c][k0];
        a[1][1] = *(const short8*)&Hb[16 + c][k0];
        #pragma unroll
        for (int th = 0; th < 3; ++th) {
            const int o = w * 16 + th * 128 + c;        // gate output row of W
            const short8 bi = *(const short8*)(WbIH + (size_t)o * DIM + k0);
            const short8 bh = *(const short8*)(WbHH + (size_t)o * DIM + k0);
            #pragma unroll
            for (int mt = 0; mt < 2; ++mt) {
                acc[mt][th][0] = __builtin_amdgcn_mfma_f32_16x16x32_bf16(a[mt][0], bi, acc[mt][th][0], 0, 0, 0);
                acc[mt][th][1] = __builtin_amdgcn_mfma_f32_16x16x32_bf16(a[mt][1], bh, acc[mt][th][1], 0, 0, 0);
            }
        }
    }
    __syncthreads();   // Xb dead -> Hn overlay safe

    // ---- gate math; lane holds (m = mt*16 + gq*4 + r, d = 16w + c) ----
    const int d = w * 16 + c;
    const float bs_r = b_ih[d]       + b_hh[d];
    const float bs_z = b_ih[d + 128] + b_hh[d + 128];
    const float bi_n = b_ih[d + 256];
    const float bh_n = b_hh[d + 256];

    #pragma unroll
    for (int mt = 0; mt < 2; ++mt) {
        #pragma unroll
        for (int r = 0; r < 4; ++r) {
            const int m = mt * 16 + gq * 4 + r;
            float s_r  = acc[mt][0][0][r] + acc[mt][0][1][r] + bs_r;
            float s_z  = acc[mt][1][0][r] + acc[mt][1][1][r] + bs_z;
            float gi_n = acc[mt][2][0][r] + bi_n;
            float gh_n = acc[mt][2][1][r] + bh_n;
            float rg = 1.f / (1.f + __expf(-s_r));
            float zg = 1.f / (1.f + __expf(-s_z));
            float aa = gi_n + rg * gh_n;
            float n  = 1.f - 2.f / (__expf(2.f * aa) + 1.f);   // tanh, inf-safe
            float h  = bf2f(Hb[m][d]);
            Hn[m][d] = f2bf((1.f - zg) * n + zg * h);
        }
    }
    __syncthreads();

    // ---- epilogue: LDS reads, sequential coalesced nontemporal stores ----
    #pragma unroll
    for (int jj = 0; jj < 2; ++jj) {
        int j = t + jj * 512;
        int row = j >> 5, c4 = j & 31;
        if (rinfo[row] < 0) continue;                  // copied at stage
        size_t off = (size_t)(rb + row) * DIM + c4 * 4;
        short4_t hns = *(short4_t*)&Hn[row][c4 * 4];
        short4_t hs  = *(short4_t*)&Hb[row][c4 * 4];
        short4_t vs  = *(short4_t*)&Vb[row][c4 * 4];
        f32x4 hn, var;
        hn.x = bf2f(hns.x); hn.y = bf2f(hns.y); hn.z = bf2f(hns.z); hn.w = bf2f(hns.w);
        float dx = hn.x - bf2f(hs.x), dy = hn.y - bf2f(hs.y);
        float dz = hn.z - bf2f(hs.z), dw = hn.w - bf2f(hs.w);
        var.x = 0.9f * bf2f(vs.x) + 0.1f * dx * dx;
        var.y = 0.9f * bf2f(vs.y) + 0.1f * dy * dy;
        var.z = 0.9f * bf2f(vs.z) + 0.1f * dz * dz;
        var.w = 0.9f * bf2f(vs.w) + 0.1f * dw * dw;
        nts(out0 + off, hn);
        nts(out1 + off, var);
    }
}

// ----------------------------------------------- fallback: R5 structure ----
__global__ void __launch_bounds__(256)
k_copy(const float* __restrict__ hidden,
       const float* __restrict__ variance,
       const unsigned char* __restrict__ mask,   // null -> copy all
       float* __restrict__ out0,
       float* __restrict__ out1) {
    int gid = blockIdx.x * 256 + threadIdx.x;
    int row = gid >> 4;
    int c8  = gid & 15;
    if (mask && mask[row]) return;
    size_t off = (size_t)row * DIM + c8 * 8;
    f32x4 a0 = *(const f32x4*)(hidden + off);
    f32x4 a1 = *(const f32x4*)(hidden + off + 4);
    f32x4 b0 = *(const f32x4*)(variance + off);
    f32x4 b1 = *(const f32x4*)(variance + off + 4);
    *(f32x4*)(out0 + off)     = a0;
    *(f32x4*)(out0 + off + 4) = a1;
    *(f32x4*)(out1 + off)     = b0;
    *(f32x4*)(out1 + off + 4) = b1;
}

__global__ void __launch_bounds__(512)
k_gru(const float* __restrict__ hidden,
      const float* __restrict__ variance,
      const int*   __restrict__ idx,
      const float* __restrict__ xg,
      const short* __restrict__ WbIH,
      const short* __restrict__ WbHH,
      const float* __restrict__ b_ih,
      const float* __restrict__ b_hh,
      float* __restrict__ out0,
      float* __restrict__ out1) {
    __shared__ __align__(16) char smem[26112];
    short (*Xb)[136] = (short(*)[136])smem;
    short (*Hb)[136] = (short(*)[136])(smem + 8704);
    short (*Vb)[136] = (short(*)[136])(smem + 17408);
    short (*Hn)[136] = (short(*)[136])smem;

    const int t  = threadIdx.x;
    const int rb = blockIdx.x * 32;

    #pragma unroll
    for (int jj = 0; jj < 2; ++jj) {
        int j = t + jj * 512;
        int row = j >> 5, c4 = j & 31;
        int node = idx[rb + row];
        f32x4 xv = *(const f32x4*)(xg + (size_t)(rb + row) * DIM + c4 * 4);
        f32x4 hv = *(const f32x4*)(hidden + (size_t)node * DIM + c4 * 4);
        f32x4 vv = *(const f32x4*)(variance + (size_t)node * DIM + c4 * 4);
        short4_t xs, hs, vs;
        xs.x = f2bf(xv.x); xs.y = f2bf(xv.y); xs.z = f2bf(xv.z); xs.w = f2bf(xv.w);
        hs.x = f2bf(hv.x); hs.y = f2bf(hv.y); hs.z = f2bf(hv.z); hs.w = f2bf(hv.w);
        vs.x = f2bf(vv.x); vs.y = f2bf(vv.y); vs.z = f2bf(vv.z); vs.w = f2bf(vv.w);
        *(short4_t*)&Xb[row][c4 * 4] = xs;
        *(short4_t*)&Hb[row][c4 * 4] = hs;
        *(short4_t*)&Vb[row][c4 * 4] = vs;
    }
    __syncthreads();

    const int w  = t >> 6;
    const int l  = t & 63;
    const int c  = l & 15;
    const int gq = l >> 4;

    f32x4 acc[2][3][2] = {};
    #pragma unroll
    for (int ks = 0; ks < 4; ++ks) {
        const int k0 = ks * 32 + gq * 8;
        short8 a[2][2];
        a[0][0] = *(const short8*)&Xb[c][k0];
        a[1][0] = *(const short8*)&Xb[16 + c][k0];
        a[0][1] = *(const short8*)&Hb[c][k0];
        a[1][1] = *(const short8*)&Hb[16 + c][k0];
        #pragma unroll
        for (int th = 0; th < 3; ++th) {
            const int o = w * 16 + th * 128 + c;
            const short8 bi = *(const short8*)(WbIH + (size_t)o * DIM + k0);
            const short8 bh = *(const short8*)(WbHH + (size_t)o * DIM + k0);
            #pragma unroll
            for (int mt = 0; mt < 2; ++mt) {
                acc[mt][th][0] = __builtin_amdgcn_mfma_f32_16x16x32_bf16(a[mt][0], bi, acc[mt][th][0], 0, 0, 0);
                acc[mt][th][1] = __builtin_amdgcn_mfma_f32_16x16x32_bf16(a[mt][1], bh, acc[mt][th][1], 0, 0, 0);
            }
        }
    }
    __syncthreads();

    const int d = w * 16 + c;
    const float bs_r = b_ih[d]       + b_hh[d];
    const float bs_z = b_ih[d + 128] + b_hh[d + 128];
    const float bi_n = b_ih[d + 256];
    const float bh_n = b_hh[d + 256];
    #pragma unroll
    for (int mt = 0; mt < 2; ++mt) {
        #pragma unroll
        for (int r = 0; r < 4; ++r) {
            const int m = mt * 16 + gq * 4 + r;
            float s_r  = acc[mt][0][0][r] + acc[mt][0][1][r] + bs_r;
            float s_z  = acc[mt][1][0][r] + acc[mt][1][1][r] + bs_z;
            float gi_n = acc[mt][2][0][r] + bi_n;
            float gh_n = acc[mt][2][1][r] + bh_n;
            float rg = 1.f / (1.f + __expf(-s_r));
            float zg = 1.f / (1.f + __expf(-s_z));
            float aa = gi_n + rg * gh_n;
            float n  = 1.f - 2.f / (__expf(2.f * aa) + 1.f);
            float h  = bf2f(Hb[m][d]);
            Hn[m][d] = f2bf((1.f - zg) * n + zg * h);
        }
    }
    __syncthreads();

    #pragma unroll
    for (int jj = 0; jj < 2; ++jj) {
        int j = t + jj * 512;
        int row = j >> 5, c4 = j & 31;
        int node = idx[rb + row];
        size_t off = (size_t)node * DIM + c4 * 4;
        short4_t hns = *(short4_t*)&Hn[row][c4 * 4];
        short4_t hs  = *(short4_t*)&Hb[row][c4 * 4];
        short4_t vs  = *(short4_t*)&Vb[row][c4 * 4];
        f32x4 hn, var;
        hn.x = bf2f(hns.x); hn.y = bf2f(hns.y); hn.z = bf2f(hns.z); hn.w = bf2f(hns.w);
        float dx = hn.x - bf2f(hs.x), dy = hn.y - bf2f(hs.y);
        float dz = hn.z - bf2f(hs.z), dw = hn.w - bf2f(hs.w);
        var.x = 0.9f * bf2f(vs.x) + 0.1f * dx * dx;
        var.y = 0.9f * bf2f(vs.y) + 0.1f * dy * dy;
        var.z = 0.9f * bf2f(vs.z) + 0.1f * dz * dz;
        var.w = 0.9f * bf2f(vs.w) + 0.1f * dw * dw;
        *(f32x4*)(out0 + off) = hn;
        *(f32x4*)(out1 + off) = var;
    }
}

// -------------------------------------------------------------- launch ----
extern "C" void kernel_launch(void* const* d_in, const int* in_sizes, int n_in,
                              void* d_out, int out_size, void* d_ws, size_t ws_size,
                              hipStream_t stream) {
    const float* hidden   = (const float*)d_in[0];
    const float* variance = (const float*)d_in[1];
    const int*   idx      = (const int*)d_in[2];
    const float* x        = (const float*)d_in[3];
    const float* Wih      = (const float*)d_in[4];
    const float* Whh      = (const float*)d_in[5];
    const float* bih      = (const float*)d_in[6];
    const float* bhh      = (const float*)d_in[7];
    float* out0 = (float*)d_out;
    float* out1 = out0 + (size_t)NUM_NODES * DIM;

    const size_t invB  = (size_t)NUM_NODES * 4;          // 2,000,000
    const size_t maskB = (size_t)NUM_NODES;              // 500,000
    const size_t wB    = (size_t)3 * DIM * DIM * 2;      // 196,608 per matrix

    const bool full = ws_size >= invB + 2 * wB;          // streaming path
    const bool mid  = !full && ws_size >= maskB + 16 + 2 * wB;

    if (full) {
        int*   inv  = (int*)d_ws;
        short* WbIH = (short*)((char*)d_ws + invB);      // invB % 16 == 0
        short* WbHH = WbIH + 3 * DIM * DIM;
        k_init<<<(NUM_NODES + 255) / 256, 256, 0, stream>>>(
            inv, nullptr, Wih, Whh, WbIH, WbHH);
        k_scatter<<<BATCH / 256, 256, 0, stream>>>(inv, nullptr, idx);
        k_stream<<<NBLK, 512, 0, stream>>>(hidden, variance, inv, x,
                                           WbIH, WbHH, bih, bhh, out0, out1);
    } else if (mid) {
        unsigned char* mask = (unsigned char*)d_ws;
        short* WbIH = (short*)((char*)d_ws + ((maskB + 15) & ~size_t(15)));
        short* WbHH = WbIH + 3 * DIM * DIM;
        k_init<<<(NUM_NODES + 255) / 256, 256, 0, stream>>>(
            nullptr, mask, Wih, Whh, WbIH, WbHH);
        k_scatter<<<BATCH / 256, 256, 0, stream>>>(nullptr, mask, idx);
        k_copy<<<(NUM_NODES * 16) / 256, 256, 0, stream>>>(
            hidden, variance, mask, out0, out1);
        k_gru<<<BATCH / 32, 512, 0, stream>>>(hidden, variance, idx, x,
                                              WbIH, WbHH, bih, bhh, out0, out1);
    } else {
        short* WbIH = (short*)d_ws;
        short* WbHH = WbIH + 3 * DIM * DIM;
        k_init<<<(NUM_NODES + 255) / 256, 256, 0, stream>>>(
            nullptr, nullptr, Wih, Whh, WbIH, WbHH);
        k_copy<<<(NUM_NODES * 16) / 256, 256, 0, stream>>>(
            hidden, variance, nullptr, out0, out1);
        k_gru<<<BATCH / 32, 512, 0, stream>>>(hidden, variance, idx, x,
                                              WbIH, WbHH, bih, bhh, out0, out1);
    }
}